// Round 19
// baseline (153.843 us; speedup 1.0000x reference)
//
#include <hip/hip_runtime.h>

typedef _Float16 f16;
typedef _Float16 half8 __attribute__((ext_vector_type(8)));
typedef _Float16 half4v __attribute__((ext_vector_type(4)));
typedef __fp16 fp16x2 __attribute__((ext_vector_type(2)));
typedef float floatx4 __attribute__((ext_vector_type(4)));
typedef unsigned int uint;

constexpr int Bsz = 4, Tseq = 2048, Cdim = 1024, NH = 16, HDim = 64;
constexpr int Mtok = Bsz * Tseq;      // 8192
constexpr int NQT = Tseq / 64;        // 32 q-tiles
constexpr float QSCALE = 0.18033688f; // 0.125 * log2(e)

#define GLDS16(src, dst) __builtin_amdgcn_global_load_lds( \
    (const __attribute__((address_space(1))) void*)(src),  \
    (__attribute__((address_space(3))) void*)(dst), 16, 0, 0)

__device__ __forceinline__ float fexp2(float x) { return __builtin_amdgcn_exp2f(x); }
__device__ __forceinline__ uint pkrtz(float a, float b) {
  fp16x2 h = __builtin_amdgcn_cvt_pkrtz(a, b);
  return __builtin_bit_cast(uint, h);
}
#define MFMA16(a, b, c) __builtin_amdgcn_mfma_f32_16x16x32_f16((a), (b), (c), 0, 0, 0)

// ---------------- fused f32 -> f16 conversion (x, W_attn, W_proj) ----------------
__global__ void cvt3_kernel(const float* __restrict__ x, const float* __restrict__ wa,
                            const float* __restrict__ wp,
                            f16* __restrict__ xh, f16* __restrict__ wah, f16* __restrict__ wph) {
  constexpr int nx = Mtok * Cdim, nwa = 3 * Cdim * Cdim, nwp = Cdim * Cdim;
  int i = (blockIdx.x * blockDim.x + threadIdx.x) * 4;
  const float* src; f16* dst; int off;
  if (i < nx)            { src = x;  dst = xh;  off = i; }
  else if (i < nx + nwa) { src = wa; dst = wah; off = i - nx; }
  else                   { src = wp; dst = wph; off = i - nx - nwa; }
  float4 v = *(const float4*)(src + off);
  half4v o;
  o[0] = (f16)v.x; o[1] = (f16)v.y; o[2] = (f16)v.z; o[3] = (f16)v.w;
  *(half4v*)(dst + off) = o;
}

// ============ qk projection: 256x256 tile, 8-wave, 8-phase (R15/R17, verified) ======
__global__ __launch_bounds__(512, 2)
void qk8p_kernel(const f16* __restrict__ X, const f16* __restrict__ W,
                 f16* __restrict__ q_out, f16* __restrict__ k_out)
{
  __shared__ __align__(16) char smem[131072];
  constexpr int K = 1024, NT = 16;
  const int sbid = (blockIdx.x & 7) * 32 + (blockIdx.x >> 3);
  const int bm = sbid >> 3, bn = sbid & 7;
  const int m0 = bm * 256, n0 = bn * 256;
  const int tid = threadIdx.x, w = tid >> 6, lane = tid & 63;
  const int wr = w >> 2, wc = w & 3;
  const int g = lane >> 4, lm = lane & 15;

  const int grow = lane >> 3;
  const int cg = (lane & 7) ^ grow;

  auto stage_half = [&](int op, int t, int h) {
    const f16* src = op ? W : X;
    char* base = smem + op * 65536 + (t & 1) * 32768 + h * 16384;
    const int rbase = (op ? n0 : m0) + h * 128;
#pragma unroll
    for (int r2 = 0; r2 < 2; ++r2) {
      int row = rbase + r2 * 64 + w * 8 + grow;
      GLDS16(src + (size_t)row * K + t * 64 + cg * 8,
             base + (r2 * 64 + w * 8) * 128);
    }
  };

  floatx4 acc[8][4];
#pragma unroll
  for (int i = 0; i < 8; ++i)
#pragma unroll
    for (int j = 0; j < 4; ++j) acc[i][j] = (floatx4)0.0f;

  const int sw = lm & 7;
  const char* S = smem;
  const int Abase = wr * 16384 + lm * 128;
  const int Bbase = 65536 + (wc >> 1) * 16384 + ((wc & 1) * 64 + lm) * 128;

  half8 a0[4][2], a1[4][2], b0[2][2], b1[2][2];

  stage_half(0, 0, 0); stage_half(0, 0, 1);
  stage_half(1, 0, 0); stage_half(1, 0, 1);
  stage_half(1, 1, 0); stage_half(1, 1, 1);

#pragma unroll 2
  for (int t = 0; t < NT; ++t) {
    const int par = (t & 1) * 32768;

    if (t == NT - 1) { asm volatile("s_waitcnt vmcnt(0)" ::: "memory"); }
    else             { asm volatile("s_waitcnt vmcnt(4)" ::: "memory"); }
    __builtin_amdgcn_s_barrier();
#pragma unroll
    for (int i = 0; i < 4; ++i)
#pragma unroll
      for (int kk = 0; kk < 2; ++kk)
        a0[i][kk] = *(const half8*)(S + par + Abase + i * 2048 + 16 * ((kk * 4 + g) ^ sw));
#pragma unroll
    for (int j = 0; j < 2; ++j)
#pragma unroll
      for (int kk = 0; kk < 2; ++kk)
        b0[j][kk] = *(const half8*)(S + par + Bbase + j * 2048 + 16 * ((kk * 4 + g) ^ sw));
    if (t + 1 < NT) stage_half(0, t + 1, 0);
    asm volatile("s_waitcnt lgkmcnt(0)" ::: "memory");
    __builtin_amdgcn_sched_barrier(0);
    __builtin_amdgcn_s_setprio(1);
#pragma unroll
    for (int i = 0; i < 4; ++i)
#pragma unroll
      for (int j = 0; j < 2; ++j)
#pragma unroll
        for (int kk = 0; kk < 2; ++kk)
          acc[i][j] = MFMA16(a0[i][kk], b0[j][kk], acc[i][j]);
    __builtin_amdgcn_s_setprio(0);

    __builtin_amdgcn_s_barrier();
#pragma unroll
    for (int j = 0; j < 2; ++j)
#pragma unroll
      for (int kk = 0; kk < 2; ++kk)
        b1[j][kk] = *(const half8*)(S + par + Bbase + (j + 2) * 2048 + 16 * ((kk * 4 + g) ^ sw));
    if (t + 1 < NT) stage_half(0, t + 1, 1);
    asm volatile("s_waitcnt lgkmcnt(0)" ::: "memory");
    __builtin_amdgcn_sched_barrier(0);
    __builtin_amdgcn_s_setprio(1);
#pragma unroll
    for (int i = 0; i < 4; ++i)
#pragma unroll
      for (int j = 0; j < 2; ++j)
#pragma unroll
        for (int kk = 0; kk < 2; ++kk)
          acc[i][j + 2] = MFMA16(a0[i][kk], b1[j][kk], acc[i][j + 2]);
    __builtin_amdgcn_s_setprio(0);

    __builtin_amdgcn_s_barrier();
#pragma unroll
    for (int i = 0; i < 4; ++i)
#pragma unroll
      for (int kk = 0; kk < 2; ++kk)
        a1[i][kk] = *(const half8*)(S + par + Abase + (i + 4) * 2048 + 16 * ((kk * 4 + g) ^ sw));
    if (t + 2 < NT) stage_half(1, t + 2, 0);
    asm volatile("s_waitcnt lgkmcnt(0)" ::: "memory");
    __builtin_amdgcn_sched_barrier(0);
    __builtin_amdgcn_s_setprio(1);
#pragma unroll
    for (int i = 0; i < 4; ++i)
#pragma unroll
      for (int j = 0; j < 2; ++j)
#pragma unroll
        for (int kk = 0; kk < 2; ++kk)
          acc[i + 4][j + 2] = MFMA16(a1[i][kk], b1[j][kk], acc[i + 4][j + 2]);
    __builtin_amdgcn_s_setprio(0);

    __builtin_amdgcn_s_barrier();
    if (t + 2 < NT) stage_half(1, t + 2, 1);
    __builtin_amdgcn_s_setprio(1);
#pragma unroll
    for (int i = 0; i < 4; ++i)
#pragma unroll
      for (int j = 0; j < 2; ++j)
#pragma unroll
        for (int kk = 0; kk < 2; ++kk)
          acc[i + 4][j] = MFMA16(a1[i][kk], b0[j][kk], acc[i + 4][j]);
    __builtin_amdgcn_s_setprio(0);
  }

#pragma unroll
  for (int i = 0; i < 8; ++i) {
#pragma unroll
    for (int j = 0; j < 4; ++j) {
#pragma unroll
      for (int r = 0; r < 4; ++r) {
        int m = m0 + wr * 128 + i * 16 + 4 * g + r;
        int n = n0 + wc * 64 + j * 16 + lm;
        float v = acc[i][j][r];
        int which = n >> 10;
        int inner = n & 1023;
        int h = inner >> 6, hd = inner & 63;
        int b = m >> 11, t = m & 2047;
        if (which == 0) {
          v *= QSCALE;
          q_out[(((size_t)(b * NH + h)) * Tseq + t) * HDim + hd] = (f16)v;
        } else {
          k_out[(((size_t)(b * NH + h)) * Tseq + t) * HDim + hd] = (f16)v;
        }
      }
    }
  }
}

// ============ 128x256-tile 8-phase GEMM body (vt / proj) — R17, verified ============
template<int EPI>
__device__ __forceinline__ void g8p_body(char* smem,
    const f16* __restrict__ A, const f16* __restrict__ B,
    float* __restrict__ outF, f16* __restrict__ v_out,
    int bm, int bn)
{
  constexpr int K = 1024, NT = 16;
  const int m0 = bm * 128, n0 = bn * 256;
  const int tid = threadIdx.x, w = tid >> 6, lane = tid & 63;
  const int wr = w >> 2, wc = w & 3;
  const int g = lane >> 4, lm = lane & 15;
  const int grow = lane >> 3;
  const int cg = (lane & 7) ^ grow;

  auto stage_A = [&](int t, int h) {
    int row = m0 + h * 64 + w * 8 + grow;
    GLDS16(A + (size_t)row * K + t * 64 + cg * 8,
           smem + (t & 1) * 16384 + (h * 64 + w * 8) * 128);
  };
  auto stage_B = [&](int t, int h) {
#pragma unroll
    for (int r2 = 0; r2 < 2; ++r2) {
      int row = n0 + h * 128 + r2 * 64 + w * 8 + grow;
      GLDS16(B + (size_t)row * K + t * 64 + cg * 8,
             smem + 32768 + (t & 1) * 32768 + (h * 128 + r2 * 64 + w * 8) * 128);
    }
  };

  floatx4 acc[4][4];
#pragma unroll
  for (int i = 0; i < 4; ++i)
#pragma unroll
    for (int j = 0; j < 4; ++j) acc[i][j] = (floatx4)0.0f;

  const int sw = lm & 7;
  const char* S = smem;
  const int Abase = (wr * 64 + lm) * 128;
  const int Bbase = 32768 + (wc * 64 + lm) * 128;

  half8 a0[2][2], a1[2][2], b0[2][2], b1[2][2];

  stage_A(0, 0); stage_A(0, 1);
  stage_B(0, 0); stage_B(0, 1);
  stage_B(1, 0); stage_B(1, 1);

#pragma unroll 2
  for (int t = 0; t < NT; ++t) {
    const int parA = (t & 1) * 16384;
    const int parB = (t & 1) * 32768;

    if (t == NT - 1) { asm volatile("s_waitcnt vmcnt(0)" ::: "memory"); }
    else             { asm volatile("s_waitcnt vmcnt(4)" ::: "memory"); }
    __builtin_amdgcn_s_barrier();
#pragma unroll
    for (int i = 0; i < 2; ++i)
#pragma unroll
      for (int kk = 0; kk < 2; ++kk)
        a0[i][kk] = *(const half8*)(S + parA + Abase + i * 2048 + 16 * ((kk * 4 + g) ^ sw));
#pragma unroll
    for (int j = 0; j < 2; ++j)
#pragma unroll
      for (int kk = 0; kk < 2; ++kk)
        b0[j][kk] = *(const half8*)(S + parB + Bbase + j * 2048 + 16 * ((kk * 4 + g) ^ sw));
    if (t + 1 < NT) stage_A(t + 1, 0);
    asm volatile("s_waitcnt lgkmcnt(0)" ::: "memory");
    __builtin_amdgcn_sched_barrier(0);
    __builtin_amdgcn_s_setprio(1);
#pragma unroll
    for (int i = 0; i < 2; ++i)
#pragma unroll
      for (int j = 0; j < 2; ++j)
#pragma unroll
        for (int kk = 0; kk < 2; ++kk)
          acc[i][j] = MFMA16(a0[i][kk], b0[j][kk], acc[i][j]);
    __builtin_amdgcn_s_setprio(0);

    __builtin_amdgcn_s_barrier();
#pragma unroll
    for (int j = 0; j < 2; ++j)
#pragma unroll
      for (int kk = 0; kk < 2; ++kk)
        b1[j][kk] = *(const half8*)(S + parB + Bbase + (j + 2) * 2048 + 16 * ((kk * 4 + g) ^ sw));
    if (t + 1 < NT) stage_A(t + 1, 1);
    asm volatile("s_waitcnt lgkmcnt(0)" ::: "memory");
    __builtin_amdgcn_sched_barrier(0);
    __builtin_amdgcn_s_setprio(1);
#pragma unroll
    for (int i = 0; i < 2; ++i)
#pragma unroll
      for (int j = 0; j < 2; ++j)
#pragma unroll
        for (int kk = 0; kk < 2; ++kk)
          acc[i][j + 2] = MFMA16(a0[i][kk], b1[j][kk], acc[i][j + 2]);
    __builtin_amdgcn_s_setprio(0);

    __builtin_amdgcn_s_barrier();
#pragma unroll
    for (int i = 0; i < 2; ++i)
#pragma unroll
      for (int kk = 0; kk < 2; ++kk)
        a1[i][kk] = *(const half8*)(S + parA + Abase + (i + 2) * 2048 + 16 * ((kk * 4 + g) ^ sw));
    if (t + 2 < NT) stage_B(t + 2, 0);
    asm volatile("s_waitcnt lgkmcnt(0)" ::: "memory");
    __builtin_amdgcn_sched_barrier(0);
    __builtin_amdgcn_s_setprio(1);
#pragma unroll
    for (int i = 0; i < 2; ++i)
#pragma unroll
      for (int j = 0; j < 2; ++j)
#pragma unroll
        for (int kk = 0; kk < 2; ++kk)
          acc[i + 2][j + 2] = MFMA16(a1[i][kk], b1[j][kk], acc[i + 2][j + 2]);
    __builtin_amdgcn_s_setprio(0);

    __builtin_amdgcn_s_barrier();
    if (t + 2 < NT) stage_B(t + 2, 1);
    __builtin_amdgcn_s_setprio(1);
#pragma unroll
    for (int i = 0; i < 2; ++i)
#pragma unroll
      for (int j = 0; j < 2; ++j)
#pragma unroll
        for (int kk = 0; kk < 2; ++kk)
          acc[i + 2][j] = MFMA16(a1[i][kk], b0[j][kk], acc[i + 2][j]);
    __builtin_amdgcn_s_setprio(0);
  }

#pragma unroll
  for (int i = 0; i < 4; ++i) {
#pragma unroll
    for (int j = 0; j < 4; ++j) {
#pragma unroll
      for (int r = 0; r < 4; ++r) {
        int m = m0 + wr * 64 + i * 16 + 4 * g + r;
        int n = n0 + wc * 64 + j * 16 + lm;
        float v = acc[i][j][r];
        if constexpr (EPI == 1) {
          outF[(size_t)m * Cdim + n] = v;
        } else {
          int h = m >> 6, hd = m & 63;
          int b = n >> 11, tt = n & 2047;
          v_out[(((size_t)(b * NH + h)) * HDim + hd) * Tseq + tt] = (f16)v;
        }
      }
    }
  }
}

// V^T: A=W_v (8 bm), B=x (32 bn); per XCD: 4 bn x all bm
__global__ __launch_bounds__(512, 2)
void vt8p_kernel(const f16* __restrict__ xh, const f16* __restrict__ wVh, f16* __restrict__ Vth) {
  __shared__ __align__(16) char smem[98304];
  const int x = blockIdx.x & 7, q = blockIdx.x >> 3;
  int bn = x * 4 + (q >> 3);
  int bm = q & 7;
  g8p_body<2>(smem, wVh, xh, nullptr, Vth, bm, bn);
}

// proj: A=y (64 bm), B=W_p (4 bn); per XCD: 8 bm x all bn
__global__ __launch_bounds__(512, 2)
void proj8p_kernel(const f16* __restrict__ yh, const f16* __restrict__ wPh, float* __restrict__ out) {
  __shared__ __align__(16) char smem[98304];
  const int x = blockIdx.x & 7, q = blockIdx.x >> 3;
  int bm = x * 8 + (q >> 2);
  int bn = q & 3;
  g8p_body<1>(smem, yh, wPh, out, nullptr, bm, bn);
}

// ---------------- causal flash attention: affine phase loops (R18, verified) -------
__device__ __forceinline__ void softmax_tile(floatx4* s,
                                             bool diag, int j0, int qg, char* pwrow, int g, int lm) {
  if (diag) {
#pragma unroll
    for (int nf = 0; nf < 4; ++nf)
#pragma unroll
      for (int r = 0; r < 4; ++r)
        if (j0 + nf * 16 + 4 * g + r > qg) s[nf][r] = -1e30f;
  }
#pragma unroll
  for (int nf = 0; nf < 4; ++nf) {
    float p0 = fexp2(s[nf][0]), p1 = fexp2(s[nf][1]);
    float p2 = fexp2(s[nf][2]), p3 = fexp2(s[nf][3]);
    uint lo = pkrtz(p0, p1), hi = pkrtz(p2, p3);
    int slot = 2 * nf + (g >> 1);
    uint2 u; u.x = lo; u.y = hi;
    *(uint2*)(pwrow + 16 * (slot ^ (lm & 7)) + 8 * (g & 1)) = u;
  }
}

__device__ __forceinline__ void store_o(const floatx4* acc, const floatx4 l5, int q0w,
                                        int g, int lm, f16* __restrict__ Y, int b, int h) {
#pragma unroll
  for (int r = 0; r < 4; ++r) {
    float inv = 1.0f / l5[r];
    int t = q0w + 4 * g + r;
    size_t base = ((size_t)(b * Tseq + t)) * Cdim + h * HDim;
#pragma unroll
    for (int ng = 0; ng < 4; ++ng)
      Y[base + ng * 16 + lm] = (f16)(acc[ng][r] * inv);
  }
}

__global__ __launch_bounds__(256)
void attn_kernel(const f16* __restrict__ Q, const f16* __restrict__ Kg,
                 const f16* __restrict__ Vt, f16* __restrict__ Y)
{
  __shared__ __align__(16) char smem[40960];
  int wg = blockIdx.x;
  int lin = (wg & 7) * 128 + (wg >> 3);
  const int p  = lin & 15;
  const int bh = lin >> 4;
  const int itB = NQT - p;
  const f16* Qb  = Q  + (size_t)bh * Tseq * HDim;
  const f16* Kb  = Kg + (size_t)bh * Tseq * HDim;
  const f16* Vtb = Vt + (size_t)bh * HDim * Tseq;

  const int tid = threadIdx.x, w = tid >> 6, lane = tid & 63;
  const int g = lane >> 4, lm = lane & 15;
  char* pwrow = smem + 32768 + w * 2048 + lm * 128;
  const int b = bh >> 4, h = bh & 15;

  half8 ones;
#pragma unroll
  for (int i = 0; i < 8; ++i) ones[i] = (f16)1.0f;

  int q0 = (NQT - 1 - p) * 64;
  int qg = q0 + w * 16 + lm;
  half8 qf0 = *(const half8*)(Qb + (size_t)(q0 + w * 16 + lm) * HDim + g * 8);
  half8 qf1 = *(const half8*)(Qb + (size_t)(q0 + w * 16 + lm) * HDim + 32 + g * 8);

  floatx4 acc[4], acc5;
  acc5 = (floatx4)0.f;
#pragma unroll
  for (int ng = 0; ng < 4; ++ng) acc[ng] = (floatx4)0.f;

  const int srow = w * 8 + (lane >> 3);
  const int sslot = lane & 7;

  auto stage = [&](int j0s, int buf) {
#pragma unroll
    for (int t = 0; t < 2; ++t) {
      int row = srow + t * 32;
      int cg = sslot ^ (row & 7);
      GLDS16(Kb + (size_t)(j0s + row) * HDim + cg * 8,
             smem + buf * 8192 + (w * 8 + t * 32) * 128);
      GLDS16(Vtb + (size_t)row * Tseq + j0s + cg * 8,
             smem + 16384 + buf * 8192 + (w * 8 + t * 32) * 128);
    }
  };

  auto compute = [&](int j0, int par, bool diag) {
    char* kb   = smem + par * 8192;
    char* vbuf = smem + 16384 + par * 8192;
    floatx4 s[4];
    __builtin_amdgcn_s_setprio(1);
#pragma unroll
    for (int nf = 0; nf < 4; ++nf) {
      half8 kf0 = *(const half8*)(kb + (nf * 16 + lm) * 128 + 16 * ((g)     ^ (lm & 7)));
      half8 kf1 = *(const half8*)(kb + (nf * 16 + lm) * 128 + 16 * ((4 + g) ^ (lm & 7)));
      s[nf] = MFMA16(kf0, qf0, (floatx4)0.f);
      s[nf] = MFMA16(kf1, qf1, s[nf]);
    }
    __builtin_amdgcn_s_setprio(0);

    softmax_tile(s, diag, j0, qg, pwrow, g, lm);
    half8 pa0 = *(const half8*)(pwrow + 16 * ((g)     ^ (lm & 7)));
    half8 pa1 = *(const half8*)(pwrow + 16 * ((4 + g) ^ (lm & 7)));

    __builtin_amdgcn_s_setprio(1);
    acc5 = MFMA16(pa0, ones, acc5);
    acc5 = MFMA16(pa1, ones, acc5);
#pragma unroll
    for (int c = 0; c < 2; ++c)
#pragma unroll
      for (int ng = 0; ng < 4; ++ng) {
        half8 vbf = *(const half8*)(vbuf + (ng * 16 + lm) * 128 + 16 * ((4 * c + g) ^ (lm & 7)));
        acc[ng] = MFMA16(c ? pa1 : pa0, vbf, acc[ng]);
      }
    __builtin_amdgcn_s_setprio(0);
  };

  stage(0, 0);
  asm volatile("s_waitcnt vmcnt(0)" ::: "memory");
  __builtin_amdgcn_s_barrier();

  int git = 0;
  for (int jt = 0; jt < itB - 1; ++jt, ++git) {
    stage((jt + 1) * 64, (git + 1) & 1);
    compute(jt * 64, git & 1, false);
    asm volatile("s_waitcnt vmcnt(0)" ::: "memory");
    __builtin_amdgcn_s_barrier();
  }
  stage(0, (git + 1) & 1);
  compute((itB - 1) * 64, git & 1, true);
  asm volatile("s_waitcnt vmcnt(0)" ::: "memory");
  __builtin_amdgcn_s_barrier();
  ++git;

  store_o(acc, acc5, q0 + 16 * w, g, lm, Y, b, h);
  q0 = p * 64;
  qg = q0 + w * 16 + lm;
  qf0 = *(const half8*)(Qb + (size_t)(q0 + w * 16 + lm) * HDim + g * 8);
  qf1 = *(const half8*)(Qb + (size_t)(q0 + w * 16 + lm) * HDim + 32 + g * 8);
  acc5 = (floatx4)0.f;
#pragma unroll
  for (int ng = 0; ng < 4; ++ng) acc[ng] = (floatx4)0.f;

  for (int jt = 0; jt < p; ++jt, ++git) {
    stage((jt + 1) * 64, (git + 1) & 1);
    compute(jt * 64, git & 1, false);
    asm volatile("s_waitcnt vmcnt(0)" ::: "memory");
    __builtin_amdgcn_s_barrier();
  }
  compute(p * 64, git & 1, true);

  store_o(acc, acc5, q0 + 16 * w, g, lm, Y, b, h);
}

// ---------------- launcher ----------------
extern "C" void kernel_launch(void* const* d_in, const int* in_sizes, int n_in,
                              void* d_out, int out_size, void* d_ws, size_t ws_size,
                              hipStream_t stream)
{
  const float* x      = (const float*)d_in[0];
  const float* W_attn = (const float*)d_in[1];
  const float* W_proj = (const float*)d_in[2];
  float* out = (float*)d_out;

  char* ws = (char*)d_ws;
  f16* xh  = (f16*)(ws);
  f16* wAh = (f16*)(ws + (size_t)(16u << 20));
  f16* wPh = (f16*)(ws + (size_t)(22u << 20));
  f16* Qh  = (f16*)(ws + (size_t)(24u << 20));
  f16* Kh  = (f16*)(ws + (size_t)(40u << 20));
  f16* Vth = (f16*)(ws + (size_t)(56u << 20));  // V^T [B,H,HD,T]
  f16* yh  = xh;

  constexpr int ntot = (Mtok * Cdim + 3 * Cdim * Cdim + Cdim * Cdim) / 4;
  cvt3_kernel<<<(ntot + 255) / 256, 256, 0, stream>>>(x, W_attn, W_proj, xh, wAh, wPh);

  qk8p_kernel<<<dim3(256), 512, 0, stream>>>(xh, wAh, Qh, Kh);

  vt8p_kernel<<<dim3(256), 512, 0, stream>>>(xh, wAh + (size_t)2048 * Cdim, Vth);

  attn_kernel<<<dim3(1024), 256, 0, stream>>>(Qh, Kh, Vth, yh);

  proj8p_kernel<<<dim3(256), 512, 0, stream>>>(yh, wPh, out);
}

// Round 20
// 150.708 us; speedup vs baseline: 1.0208x; 1.0208x over previous
//
#include <hip/hip_runtime.h>

typedef _Float16 f16;
typedef _Float16 half8 __attribute__((ext_vector_type(8)));
typedef _Float16 half4v __attribute__((ext_vector_type(4)));
typedef __fp16 fp16x2 __attribute__((ext_vector_type(2)));
typedef float floatx4 __attribute__((ext_vector_type(4)));
typedef unsigned int uint;

constexpr int Bsz = 4, Tseq = 2048, Cdim = 1024, NH = 16, HDim = 64;
constexpr int Mtok = Bsz * Tseq;      // 8192
constexpr float QSCALE = 0.18033688f; // 0.125 * log2(e)

#define GLDS16(src, dst) __builtin_amdgcn_global_load_lds( \
    (const __attribute__((address_space(1))) void*)(src),  \
    (__attribute__((address_space(3))) void*)(dst), 16, 0, 0)

__device__ __forceinline__ float fexp2(float x) { return __builtin_amdgcn_exp2f(x); }
__device__ __forceinline__ uint pkrtz(float a, float b) {
  fp16x2 h = __builtin_amdgcn_cvt_pkrtz(a, b);
  return __builtin_bit_cast(uint, h);
}
#define MFMA16(a, b, c) __builtin_amdgcn_mfma_f32_16x16x32_f16((a), (b), (c), 0, 0, 0)

// ---------------- fused f32 -> f16 conversion (x, W_attn, W_proj) ----------------
__global__ void cvt3_kernel(const float* __restrict__ x, const float* __restrict__ wa,
                            const float* __restrict__ wp,
                            f16* __restrict__ xh, f16* __restrict__ wah, f16* __restrict__ wph) {
  constexpr int nx = Mtok * Cdim, nwa = 3 * Cdim * Cdim, nwp = Cdim * Cdim;
  int i = (blockIdx.x * blockDim.x + threadIdx.x) * 4;
  const float* src; f16* dst; int off;
  if (i < nx)            { src = x;  dst = xh;  off = i; }
  else if (i < nx + nwa) { src = wa; dst = wah; off = i - nx; }
  else                   { src = wp; dst = wph; off = i - nx - nwa; }
  float4 v = *(const float4*)(src + off);
  half4v o;
  o[0] = (f16)v.x; o[1] = (f16)v.y; o[2] = (f16)v.z; o[3] = (f16)v.w;
  *(half4v*)(dst + off) = o;
}

// ============ qk projection: 256x256 tile, 8-wave, 8-phase (R15/R17, verified) ======
__global__ __launch_bounds__(512, 2)
void qk8p_kernel(const f16* __restrict__ X, const f16* __restrict__ W,
                 f16* __restrict__ q_out, f16* __restrict__ k_out)
{
  __shared__ __align__(16) char smem[131072];
  constexpr int K = 1024, NT = 16;
  const int sbid = (blockIdx.x & 7) * 32 + (blockIdx.x >> 3);
  const int bm = sbid >> 3, bn = sbid & 7;
  const int m0 = bm * 256, n0 = bn * 256;
  const int tid = threadIdx.x, w = tid >> 6, lane = tid & 63;
  const int wr = w >> 2, wc = w & 3;
  const int g = lane >> 4, lm = lane & 15;

  const int grow = lane >> 3;
  const int cg = (lane & 7) ^ grow;

  auto stage_half = [&](int op, int t, int h) {
    const f16* src = op ? W : X;
    char* base = smem + op * 65536 + (t & 1) * 32768 + h * 16384;
    const int rbase = (op ? n0 : m0) + h * 128;
#pragma unroll
    for (int r2 = 0; r2 < 2; ++r2) {
      int row = rbase + r2 * 64 + w * 8 + grow;
      GLDS16(src + (size_t)row * K + t * 64 + cg * 8,
             base + (r2 * 64 + w * 8) * 128);
    }
  };

  floatx4 acc[8][4];
#pragma unroll
  for (int i = 0; i < 8; ++i)
#pragma unroll
    for (int j = 0; j < 4; ++j) acc[i][j] = (floatx4)0.0f;

  const int sw = lm & 7;
  const char* S = smem;
  const int Abase = wr * 16384 + lm * 128;
  const int Bbase = 65536 + (wc >> 1) * 16384 + ((wc & 1) * 64 + lm) * 128;

  half8 a0[4][2], a1[4][2], b0[2][2], b1[2][2];

  stage_half(0, 0, 0); stage_half(0, 0, 1);
  stage_half(1, 0, 0); stage_half(1, 0, 1);
  stage_half(1, 1, 0); stage_half(1, 1, 1);

#pragma unroll 2
  for (int t = 0; t < NT; ++t) {
    const int par = (t & 1) * 32768;

    if (t == NT - 1) { asm volatile("s_waitcnt vmcnt(0)" ::: "memory"); }
    else             { asm volatile("s_waitcnt vmcnt(4)" ::: "memory"); }
    __builtin_amdgcn_s_barrier();
#pragma unroll
    for (int i = 0; i < 4; ++i)
#pragma unroll
      for (int kk = 0; kk < 2; ++kk)
        a0[i][kk] = *(const half8*)(S + par + Abase + i * 2048 + 16 * ((kk * 4 + g) ^ sw));
#pragma unroll
    for (int j = 0; j < 2; ++j)
#pragma unroll
      for (int kk = 0; kk < 2; ++kk)
        b0[j][kk] = *(const half8*)(S + par + Bbase + j * 2048 + 16 * ((kk * 4 + g) ^ sw));
    if (t + 1 < NT) stage_half(0, t + 1, 0);
    asm volatile("s_waitcnt lgkmcnt(0)" ::: "memory");
    __builtin_amdgcn_sched_barrier(0);
    __builtin_amdgcn_s_setprio(1);
#pragma unroll
    for (int i = 0; i < 4; ++i)
#pragma unroll
      for (int j = 0; j < 2; ++j)
#pragma unroll
        for (int kk = 0; kk < 2; ++kk)
          acc[i][j] = MFMA16(a0[i][kk], b0[j][kk], acc[i][j]);
    __builtin_amdgcn_s_setprio(0);

    __builtin_amdgcn_s_barrier();
#pragma unroll
    for (int j = 0; j < 2; ++j)
#pragma unroll
      for (int kk = 0; kk < 2; ++kk)
        b1[j][kk] = *(const half8*)(S + par + Bbase + (j + 2) * 2048 + 16 * ((kk * 4 + g) ^ sw));
    if (t + 1 < NT) stage_half(0, t + 1, 1);
    asm volatile("s_waitcnt lgkmcnt(0)" ::: "memory");
    __builtin_amdgcn_sched_barrier(0);
    __builtin_amdgcn_s_setprio(1);
#pragma unroll
    for (int i = 0; i < 4; ++i)
#pragma unroll
      for (int j = 0; j < 2; ++j)
#pragma unroll
        for (int kk = 0; kk < 2; ++kk)
          acc[i][j + 2] = MFMA16(a0[i][kk], b1[j][kk], acc[i][j + 2]);
    __builtin_amdgcn_s_setprio(0);

    __builtin_amdgcn_s_barrier();
#pragma unroll
    for (int i = 0; i < 4; ++i)
#pragma unroll
      for (int kk = 0; kk < 2; ++kk)
        a1[i][kk] = *(const half8*)(S + par + Abase + (i + 4) * 2048 + 16 * ((kk * 4 + g) ^ sw));
    if (t + 2 < NT) stage_half(1, t + 2, 0);
    asm volatile("s_waitcnt lgkmcnt(0)" ::: "memory");
    __builtin_amdgcn_sched_barrier(0);
    __builtin_amdgcn_s_setprio(1);
#pragma unroll
    for (int i = 0; i < 4; ++i)
#pragma unroll
      for (int j = 0; j < 2; ++j)
#pragma unroll
        for (int kk = 0; kk < 2; ++kk)
          acc[i + 4][j + 2] = MFMA16(a1[i][kk], b1[j][kk], acc[i + 4][j + 2]);
    __builtin_amdgcn_s_setprio(0);

    __builtin_amdgcn_s_barrier();
    if (t + 2 < NT) stage_half(1, t + 2, 1);
    __builtin_amdgcn_s_setprio(1);
#pragma unroll
    for (int i = 0; i < 4; ++i)
#pragma unroll
      for (int j = 0; j < 2; ++j)
#pragma unroll
        for (int kk = 0; kk < 2; ++kk)
          acc[i + 4][j] = MFMA16(a1[i][kk], b0[j][kk], acc[i + 4][j]);
    __builtin_amdgcn_s_setprio(0);
  }

#pragma unroll
  for (int i = 0; i < 8; ++i) {
#pragma unroll
    for (int j = 0; j < 4; ++j) {
#pragma unroll
      for (int r = 0; r < 4; ++r) {
        int m = m0 + wr * 128 + i * 16 + 4 * g + r;
        int n = n0 + wc * 64 + j * 16 + lm;
        float v = acc[i][j][r];
        int which = n >> 10;
        int inner = n & 1023;
        int h = inner >> 6, hd = inner & 63;
        int b = m >> 11, t = m & 2047;
        if (which == 0) {
          v *= QSCALE;
          q_out[(((size_t)(b * NH + h)) * Tseq + t) * HDim + hd] = (f16)v;
        } else {
          k_out[(((size_t)(b * NH + h)) * Tseq + t) * HDim + hd] = (f16)v;
        }
      }
    }
  }
}

// ============ 128x256-tile 8-phase GEMM body (vt / proj) — R17, verified ============
template<int EPI>
__device__ __forceinline__ void g8p_body(char* smem,
    const f16* __restrict__ A, const f16* __restrict__ B,
    float* __restrict__ outF, f16* __restrict__ v_out,
    int bm, int bn)
{
  constexpr int K = 1024, NT = 16;
  const int m0 = bm * 128, n0 = bn * 256;
  const int tid = threadIdx.x, w = tid >> 6, lane = tid & 63;
  const int wr = w >> 2, wc = w & 3;
  const int g = lane >> 4, lm = lane & 15;
  const int grow = lane >> 3;
  const int cg = (lane & 7) ^ grow;

  auto stage_A = [&](int t, int h) {
    int row = m0 + h * 64 + w * 8 + grow;
    GLDS16(A + (size_t)row * K + t * 64 + cg * 8,
           smem + (t & 1) * 16384 + (h * 64 + w * 8) * 128);
  };
  auto stage_B = [&](int t, int h) {
#pragma unroll
    for (int r2 = 0; r2 < 2; ++r2) {
      int row = n0 + h * 128 + r2 * 64 + w * 8 + grow;
      GLDS16(B + (size_t)row * K + t * 64 + cg * 8,
             smem + 32768 + (t & 1) * 32768 + (h * 128 + r2 * 64 + w * 8) * 128);
    }
  };

  floatx4 acc[4][4];
#pragma unroll
  for (int i = 0; i < 4; ++i)
#pragma unroll
    for (int j = 0; j < 4; ++j) acc[i][j] = (floatx4)0.0f;

  const int sw = lm & 7;
  const char* S = smem;
  const int Abase = (wr * 64 + lm) * 128;
  const int Bbase = 32768 + (wc * 64 + lm) * 128;

  half8 a0[2][2], a1[2][2], b0[2][2], b1[2][2];

  stage_A(0, 0); stage_A(0, 1);
  stage_B(0, 0); stage_B(0, 1);
  stage_B(1, 0); stage_B(1, 1);

#pragma unroll 2
  for (int t = 0; t < NT; ++t) {
    const int parA = (t & 1) * 16384;
    const int parB = (t & 1) * 32768;

    if (t == NT - 1) { asm volatile("s_waitcnt vmcnt(0)" ::: "memory"); }
    else             { asm volatile("s_waitcnt vmcnt(4)" ::: "memory"); }
    __builtin_amdgcn_s_barrier();
#pragma unroll
    for (int i = 0; i < 2; ++i)
#pragma unroll
      for (int kk = 0; kk < 2; ++kk)
        a0[i][kk] = *(const half8*)(S + parA + Abase + i * 2048 + 16 * ((kk * 4 + g) ^ sw));
#pragma unroll
    for (int j = 0; j < 2; ++j)
#pragma unroll
      for (int kk = 0; kk < 2; ++kk)
        b0[j][kk] = *(const half8*)(S + parB + Bbase + j * 2048 + 16 * ((kk * 4 + g) ^ sw));
    if (t + 1 < NT) stage_A(t + 1, 0);
    asm volatile("s_waitcnt lgkmcnt(0)" ::: "memory");
    __builtin_amdgcn_sched_barrier(0);
    __builtin_amdgcn_s_setprio(1);
#pragma unroll
    for (int i = 0; i < 2; ++i)
#pragma unroll
      for (int j = 0; j < 2; ++j)
#pragma unroll
        for (int kk = 0; kk < 2; ++kk)
          acc[i][j] = MFMA16(a0[i][kk], b0[j][kk], acc[i][j]);
    __builtin_amdgcn_s_setprio(0);

    __builtin_amdgcn_s_barrier();
#pragma unroll
    for (int j = 0; j < 2; ++j)
#pragma unroll
      for (int kk = 0; kk < 2; ++kk)
        b1[j][kk] = *(const half8*)(S + parB + Bbase + (j + 2) * 2048 + 16 * ((kk * 4 + g) ^ sw));
    if (t + 1 < NT) stage_A(t + 1, 1);
    asm volatile("s_waitcnt lgkmcnt(0)" ::: "memory");
    __builtin_amdgcn_sched_barrier(0);
    __builtin_amdgcn_s_setprio(1);
#pragma unroll
    for (int i = 0; i < 2; ++i)
#pragma unroll
      for (int j = 0; j < 2; ++j)
#pragma unroll
        for (int kk = 0; kk < 2; ++kk)
          acc[i][j + 2] = MFMA16(a0[i][kk], b1[j][kk], acc[i][j + 2]);
    __builtin_amdgcn_s_setprio(0);

    __builtin_amdgcn_s_barrier();
#pragma unroll
    for (int i = 0; i < 2; ++i)
#pragma unroll
      for (int kk = 0; kk < 2; ++kk)
        a1[i][kk] = *(const half8*)(S + parA + Abase + (i + 2) * 2048 + 16 * ((kk * 4 + g) ^ sw));
    if (t + 2 < NT) stage_B(t + 2, 0);
    asm volatile("s_waitcnt lgkmcnt(0)" ::: "memory");
    __builtin_amdgcn_sched_barrier(0);
    __builtin_amdgcn_s_setprio(1);
#pragma unroll
    for (int i = 0; i < 2; ++i)
#pragma unroll
      for (int j = 0; j < 2; ++j)
#pragma unroll
        for (int kk = 0; kk < 2; ++kk)
          acc[i + 2][j + 2] = MFMA16(a1[i][kk], b1[j][kk], acc[i + 2][j + 2]);
    __builtin_amdgcn_s_setprio(0);

    __builtin_amdgcn_s_barrier();
    if (t + 2 < NT) stage_B(t + 2, 1);
    __builtin_amdgcn_s_setprio(1);
#pragma unroll
    for (int i = 0; i < 2; ++i)
#pragma unroll
      for (int j = 0; j < 2; ++j)
#pragma unroll
        for (int kk = 0; kk < 2; ++kk)
          acc[i + 2][j] = MFMA16(a1[i][kk], b0[j][kk], acc[i + 2][j]);
    __builtin_amdgcn_s_setprio(0);
  }

#pragma unroll
  for (int i = 0; i < 4; ++i) {
#pragma unroll
    for (int j = 0; j < 4; ++j) {
#pragma unroll
      for (int r = 0; r < 4; ++r) {
        int m = m0 + wr * 64 + i * 16 + 4 * g + r;
        int n = n0 + wc * 64 + j * 16 + lm;
        float v = acc[i][j][r];
        if constexpr (EPI == 1) {
          outF[(size_t)m * Cdim + n] = v;
        } else {
          int h = m >> 6, hd = m & 63;
          int b = n >> 11, tt = n & 2047;
          v_out[(((size_t)(b * NH + h)) * HDim + hd) * Tseq + tt] = (f16)v;
        }
      }
    }
  }
}

// V^T: A=W_v (8 bm), B=x (32 bn); per XCD: 4 bn x all bm
__global__ __launch_bounds__(512, 2)
void vt8p_kernel(const f16* __restrict__ xh, const f16* __restrict__ wVh, f16* __restrict__ Vth) {
  __shared__ __align__(16) char smem[98304];
  const int x = blockIdx.x & 7, q = blockIdx.x >> 3;
  int bn = x * 4 + (q >> 3);
  int bm = q & 7;
  g8p_body<2>(smem, wVh, xh, nullptr, Vth, bm, bn);
}

// proj: A=y (64 bm), B=W_p (4 bn); per XCD: 8 bm x all bn
__global__ __launch_bounds__(512, 2)
void proj8p_kernel(const f16* __restrict__ yh, const f16* __restrict__ wPh, float* __restrict__ out) {
  __shared__ __align__(16) char smem[98304];
  const int x = blockIdx.x & 7, q = blockIdx.x >> 3;
  int bm = x * 8 + (q >> 2);
  int bn = q & 3;
  g8p_body<1>(smem, yh, wPh, out, nullptr, bm, bn);
}

// ---------------- causal flash attention: 32 q-rows per wave ----------------
// QBLK=128 (4 waves x 32 q, two 16-row fragments per wave), KVBLK=64, paired
// causal q-tiles over 16 tiles of 128 -> 512 blocks x uniform 34 iterations.
// The same 8 K-reads and 8 V-reads per iteration feed 2x the MFMA (K/V-read
// amortization: LDS pipe demand per P-entry -45%, barriers per entry halved).
// LDS 64KB: K dbuf 2x8K @0 | V^T dbuf 2x8K @16K | P 4 waves x 8K @32K.
__global__ __launch_bounds__(256)
void attn_kernel(const f16* __restrict__ Q, const f16* __restrict__ Kg,
                 const f16* __restrict__ Vt, f16* __restrict__ Y)
{
  __shared__ __align__(16) char smem[65536];
  int wg = blockIdx.x;
  int lin = (wg & 7) * 64 + (wg >> 3);   // XCD remap: XCD owns 8 bh, KV set 4MB
  const int pp = lin & 7;
  const int bh = lin >> 3;
  const int itB = 2 * (16 - pp);         // phase B iterations (q-tile 15-pp)
  const int itA = 2 * (pp + 1);          // phase A iterations (q-tile pp)
  const f16* Qb  = Q  + (size_t)bh * Tseq * HDim;
  const f16* Kb  = Kg + (size_t)bh * Tseq * HDim;
  const f16* Vtb = Vt + (size_t)bh * HDim * Tseq;

  const int tid = threadIdx.x, w = tid >> 6, lane = tid & 63;
  const int g = lane >> 4, lm = lane & 15;
  char* pw = smem + 32768 + w * 8192;    // wave's P tile: 32 rows x 128B
  const int b = bh >> 4, h = bh & 15;

  half8 ones;
#pragma unroll
  for (int i = 0; i < 8; ++i) ones[i] = (f16)1.0f;

  int q0 = (15 - pp) * 128;              // phase B q base
  half8 qA0, qA1, qB0, qB1;              // frag0: q=q0w+lm, frag1: q=q0w+16+lm
  int qg0, qg1;
  auto loadq = [&](int q0_) {
    const f16* p0 = Qb + (size_t)(q0_ + w * 32 + lm) * HDim;
    const f16* p1 = Qb + (size_t)(q0_ + w * 32 + 16 + lm) * HDim;
    qA0 = *(const half8*)(p0 + g * 8);  qA1 = *(const half8*)(p0 + 32 + g * 8);
    qB0 = *(const half8*)(p1 + g * 8);  qB1 = *(const half8*)(p1 + 32 + g * 8);
    qg0 = q0_ + w * 32 + lm;  qg1 = qg0 + 16;
  };
  loadq(q0);

  floatx4 acc[2][4], acc5[2];
#pragma unroll
  for (int f = 0; f < 2; ++f) {
    acc5[f] = (floatx4)0.f;
#pragma unroll
    for (int ng = 0; ng < 4; ++ng) acc[f][ng] = (floatx4)0.f;
  }

  const int srow = w * 8 + (lane >> 3);
  const int sslot = lane & 7;

  auto stage = [&](int j0s, int buf) {
#pragma unroll
    for (int t = 0; t < 2; ++t) {
      int row = srow + t * 32;
      int cg = sslot ^ (row & 7);
      GLDS16(Kb + (size_t)(j0s + row) * HDim + cg * 8,
             smem + buf * 8192 + (w * 8 + t * 32) * 128);
      GLDS16(Vtb + (size_t)row * Tseq + j0s + cg * 8,
             smem + 16384 + buf * 8192 + (w * 8 + t * 32) * 128);
    }
  };

  auto compute = [&](int j0, int par, bool diag) {
    char* kb   = smem + par * 8192;
    char* vbuf = smem + 16384 + par * 8192;
    floatx4 s[2][4];
    __builtin_amdgcn_s_setprio(1);
#pragma unroll
    for (int nf = 0; nf < 4; ++nf) {
      half8 kf0 = *(const half8*)(kb + (nf * 16 + lm) * 128 + 16 * ((g)     ^ (lm & 7)));
      half8 kf1 = *(const half8*)(kb + (nf * 16 + lm) * 128 + 16 * ((4 + g) ^ (lm & 7)));
      s[0][nf] = MFMA16(kf0, qA0, (floatx4)0.f);
      s[0][nf] = MFMA16(kf1, qA1, s[0][nf]);
      s[1][nf] = MFMA16(kf0, qB0, (floatx4)0.f);
      s[1][nf] = MFMA16(kf1, qB1, s[1][nf]);
    }
    __builtin_amdgcn_s_setprio(0);

#pragma unroll
    for (int f = 0; f < 2; ++f) {
      const int qgf = f ? qg1 : qg0;
      char* prow = pw + f * 2048 + lm * 128;
      if (diag) {
#pragma unroll
        for (int nf = 0; nf < 4; ++nf)
#pragma unroll
          for (int r = 0; r < 4; ++r)
            if (j0 + nf * 16 + 4 * g + r > qgf) s[f][nf][r] = -1e30f;
      }
#pragma unroll
      for (int nf = 0; nf < 4; ++nf) {
        float p0 = fexp2(s[f][nf][0]), p1 = fexp2(s[f][nf][1]);
        float p2 = fexp2(s[f][nf][2]), p3 = fexp2(s[f][nf][3]);
        uint lo = pkrtz(p0, p1), hi = pkrtz(p2, p3);
        int slot = 2 * nf + (g >> 1);
        uint2 u; u.x = lo; u.y = hi;
        *(uint2*)(prow + 16 * (slot ^ (lm & 7)) + 8 * (g & 1)) = u;
      }
    }

    half8 pa[2][2];
#pragma unroll
    for (int f = 0; f < 2; ++f) {
      pa[f][0] = *(const half8*)(pw + f * 2048 + lm * 128 + 16 * ((g)     ^ (lm & 7)));
      pa[f][1] = *(const half8*)(pw + f * 2048 + lm * 128 + 16 * ((4 + g) ^ (lm & 7)));
    }

    __builtin_amdgcn_s_setprio(1);
    acc5[0] = MFMA16(pa[0][0], ones, acc5[0]);
    acc5[0] = MFMA16(pa[0][1], ones, acc5[0]);
    acc5[1] = MFMA16(pa[1][0], ones, acc5[1]);
    acc5[1] = MFMA16(pa[1][1], ones, acc5[1]);
#pragma unroll
    for (int c = 0; c < 2; ++c)
#pragma unroll
      for (int ng = 0; ng < 4; ++ng) {
        half8 vbf = *(const half8*)(vbuf + (ng * 16 + lm) * 128 + 16 * ((4 * c + g) ^ (lm & 7)));
        acc[0][ng] = MFMA16(pa[0][c], vbf, acc[0][ng]);   // shared V read, 2 frags
        acc[1][ng] = MFMA16(pa[1][c], vbf, acc[1][ng]);
      }
    __builtin_amdgcn_s_setprio(0);
  };

  auto store_both = [&]() {
#pragma unroll
    for (int f = 0; f < 2; ++f) {
#pragma unroll
      for (int r = 0; r < 4; ++r) {
        float inv = 1.0f / acc5[f][r];
        int t = q0 + w * 32 + f * 16 + 4 * g + r;
        size_t base = ((size_t)(b * Tseq + t)) * Cdim + h * HDim;
#pragma unroll
        for (int ng = 0; ng < 4; ++ng)
          Y[base + ng * 16 + lm] = (f16)(acc[f][ng][r] * inv);
      }
    }
  };

  // prologue
  stage(0, 0);
  asm volatile("s_waitcnt vmcnt(0)" ::: "memory");
  __builtin_amdgcn_s_barrier();

  int git = 0;
  // phase B main (no diag)
  for (int jt = 0; jt < itB - 2; ++jt, ++git) {
    stage((jt + 1) * 64, (git + 1) & 1);
    compute(jt * 64, git & 1, false);
    asm volatile("s_waitcnt vmcnt(0)" ::: "memory");
    __builtin_amdgcn_s_barrier();
  }
  // phase B diag iters (last two kv-tiles straddle the diagonal)
  stage((itB - 1) * 64, (git + 1) & 1);
  compute((itB - 2) * 64, git & 1, true);
  asm volatile("s_waitcnt vmcnt(0)" ::: "memory");
  __builtin_amdgcn_s_barrier();
  ++git;
  stage(0, (git + 1) & 1);                 // phase A tile 0
  compute((itB - 1) * 64, git & 1, true);
  asm volatile("s_waitcnt vmcnt(0)" ::: "memory");
  __builtin_amdgcn_s_barrier();
  ++git;

  store_both();
  q0 = pp * 128;
  loadq(q0);
#pragma unroll
  for (int f = 0; f < 2; ++f) {
    acc5[f] = (floatx4)0.f;
#pragma unroll
    for (int ng = 0; ng < 4; ++ng) acc[f][ng] = (floatx4)0.f;
  }

  // phase A main (no diag)
  for (int jt = 0; jt < itA - 2; ++jt, ++git) {
    stage((jt + 1) * 64, (git + 1) & 1);
    compute(jt * 64, git & 1, false);
    asm volatile("s_waitcnt vmcnt(0)" ::: "memory");
    __builtin_amdgcn_s_barrier();
  }
  // phase A diag iters
  stage((itA - 1) * 64, (git + 1) & 1);
  compute((itA - 2) * 64, git & 1, true);
  asm volatile("s_waitcnt vmcnt(0)" ::: "memory");
  __builtin_amdgcn_s_barrier();
  ++git;
  compute((itA - 1) * 64, git & 1, true);

  store_both();
}

// ---------------- launcher ----------------
extern "C" void kernel_launch(void* const* d_in, const int* in_sizes, int n_in,
                              void* d_out, int out_size, void* d_ws, size_t ws_size,
                              hipStream_t stream)
{
  const float* x      = (const float*)d_in[0];
  const float* W_attn = (const float*)d_in[1];
  const float* W_proj = (const float*)d_in[2];
  float* out = (float*)d_out;

  char* ws = (char*)d_ws;
  f16* xh  = (f16*)(ws);
  f16* wAh = (f16*)(ws + (size_t)(16u << 20));
  f16* wPh = (f16*)(ws + (size_t)(22u << 20));
  f16* Qh  = (f16*)(ws + (size_t)(24u << 20));
  f16* Kh  = (f16*)(ws + (size_t)(40u << 20));
  f16* Vth = (f16*)(ws + (size_t)(56u << 20));  // V^T [B,H,HD,T]
  f16* yh  = xh;

  constexpr int ntot = (Mtok * Cdim + 3 * Cdim * Cdim + Cdim * Cdim) / 4;
  cvt3_kernel<<<(ntot + 255) / 256, 256, 0, stream>>>(x, W_attn, W_proj, xh, wAh, wPh);

  qk8p_kernel<<<dim3(256), 512, 0, stream>>>(xh, wAh, Qh, Kh);

  vt8p_kernel<<<dim3(256), 512, 0, stream>>>(xh, wAh + (size_t)2048 * Cdim, Vth);

  attn_kernel<<<dim3(512), 256, 0, stream>>>(Qh, Kh, Vth, yh);

  proj8p_kernel<<<dim3(256), 512, 0, stream>>>(yh, wPh, out);
}